// Round 12
// baseline (185.260 us; speedup 1.0000x reference)
//
#include <hip/hip_runtime.h>
#include <math.h>

constexpr int Bc = 2, Kc = 8, HWc = 16384;
constexpr float SCALE  = 0.17677669529663687f;  // 1/sqrt(32)
constexpr float INV127 = 1.0f / 127.0f;

using short8 = __attribute__((ext_vector_type(8))) short;
using f32x4  = __attribute__((ext_vector_type(4))) float;

// ws layout (floats). owt = combined (attn_w @ layer_w), d-major: owt[d][e].
constexpr int OWQ1 = 0;
constexpr int OBQ1 = OWQ1 + 130 * 128;
constexpr int OWK1 = OBQ1 + 128;
constexpr int OBK1 = OWK1 + 130 * 128;
constexpr int OWQ2 = OBK1 + 128;
constexpr int OBQ2 = OWQ2 + 258 * 128;
constexpr int OWK2 = OBQ2 + 128;
constexpr int OBK2 = OWK2 + 258 * 128;
constexpr int OPACK = OBK2 + 128;       // short region: packed MFMA A-fragments
constexpr int PQ1 = 0;
constexpr int PQ2 = PQ1 + 32 * 512;
constexpr int PY1 = PQ2 + 64 * 512;
constexpr int PY2 = PY1 + 32 * 512;

__device__ __forceinline__ unsigned bfpack(float a, float b) {
    unsigned ua = __float_as_uint(a); ua = (ua + 0x7FFFu + ((ua >> 16) & 1u)) >> 16;
    unsigned ub = __float_as_uint(b); ub = (ub + 0x7FFFu + ((ub >> 16) & 1u)) >> 16;
    return ua | (ub << 16);
}
__device__ __forceinline__ short bf1(float a) {
    unsigned ua = __float_as_uint(a); ua = (ua + 0x7FFFu + ((ua >> 16) & 1u)) >> 16;
    return (short)ua;
}
__device__ __forceinline__ float bflo(unsigned u) { return __uint_as_float(u << 16); }
__device__ __forceinline__ float bfhi(unsigned u) { return __uint_as_float(u & 0xFFFF0000u); }
__device__ __forceinline__ float bf2f(short s) {
    return __uint_as_float(((unsigned)(unsigned short)s) << 16);
}

__device__ __forceinline__ void fma16(float (&a)[4][4], uint2 u, float4 x) {
    const float y0 = bflo(u.x), y1 = bfhi(u.x), y2 = bflo(u.y), y3 = bfhi(u.y);
    a[0][0] += y0 * x.x; a[0][1] += y0 * x.y; a[0][2] += y0 * x.z; a[0][3] += y0 * x.w;
    a[1][0] += y1 * x.x; a[1][1] += y1 * x.y; a[1][2] += y1 * x.z; a[1][3] += y1 * x.w;
    a[2][0] += y2 * x.x; a[2][1] += y2 * x.y; a[2][2] += y2 * x.z; a[2][3] += y2 * x.w;
    a[3][0] += y3 * x.x; a[3][1] += y3 * x.y; a[3][2] += y3 * x.z; a[3][3] += y3 * x.w;
}

// ---------------------------------------------------------------------------
__global__ __launch_bounds__(128) void prep_kernel(
    const float* __restrict__ q1w, const float* __restrict__ q1b,
    const float* __restrict__ k1w, const float* __restrict__ k1b,
    const float* __restrict__ a1qw, const float* __restrict__ a1qb,
    const float* __restrict__ a1kw, const float* __restrict__ a1kb,
    const float* __restrict__ q2w, const float* __restrict__ q2b,
    const float* __restrict__ k2w, const float* __restrict__ k2b,
    const float* __restrict__ a2qw, const float* __restrict__ a2qb,
    const float* __restrict__ a2kw, const float* __restrict__ a2kb,
    float* __restrict__ ws)
{
    const int job = blockIdx.x / 260;
    const int d   = blockIdx.x % 260;
    const float *aw, *ab, *w, *wb;
    float *owt, *ob;
    int D;
    if (job == 0)      { aw=a1qw; ab=a1qb; w=q1w; wb=q1b; owt=ws+OWQ1; ob=ws+OBQ1; D=130; }
    else if (job == 1) { aw=a1kw; ab=a1kb; w=k1w; wb=k1b; owt=ws+OWK1; ob=ws+OBK1; D=130; }
    else if (job == 2) { aw=a2qw; ab=a2qb; w=q2w; wb=q2b; owt=ws+OWQ2; ob=ws+OBQ2; D=258; }
    else               { aw=a2kw; ab=a2kb; w=k2w; wb=k2b; owt=ws+OWK2; ob=ws+OBK2; D=258; }
    const int e = threadIdx.x;
    if (d < D) {
        float acc = 0.f;
        for (int f = 0; f < 128; ++f) acc += aw[e * 128 + f] * w[f * D + d];
        owt[d * 128 + e] = acc;
    } else if (d == D) {
        float acc = ab[e];
        for (int f = 0; f < 128; ++f) acc += aw[e * 128 + f] * wb[f];
        ob[e] = acc;
    }
}

// ---------------------------------------------------------------------------
// pack: MFMA A-fragments (bf16): element(lane,idx) = A[i][k],
// i = lane&15, k = 8*(lane>>4)+idx.
// ---------------------------------------------------------------------------
__global__ __launch_bounds__(64) void pack_kernel(float* __restrict__ ws)
{
    short* pk = (short*)(ws + OPACK);
    const int l = threadIdx.x, bid = blockIdx.x;
    const float* w;
    short* dst;
    short v[8];
    if (bid < 32) {                       // Q1 (NKT=4)
        const int et = bid >> 2, kt = bid & 3;
        w = ws + OWQ1;
        dst = pk + PQ1 + ((size_t)(et * 4 + kt) * 64 + l) * 8;
        #pragma unroll
        for (int idx = 0; idx < 8; ++idx)
            v[idx] = bf1(w[(kt * 32 + (l >> 4) * 8 + idx) * 128 + et * 16 + (l & 15)]);
    } else if (bid < 96) {                // Q2 (NKT=8)
        const int b2 = bid - 32, et = b2 >> 3, kt = b2 & 7;
        w = ws + OWQ2;
        dst = pk + PQ2 + ((size_t)(et * 8 + kt) * 64 + l) * 8;
        #pragma unroll
        for (int idx = 0; idx < 8; ++idx)
            v[idx] = bf1(w[(kt * 32 + (l >> 4) * 8 + idx) * 128 + et * 16 + (l & 15)]);
    } else if (bid < 128) {               // Y1 (8 ct x 4 h)
        const int b2 = bid - 96, ct = b2 >> 2, h = b2 & 3;
        w = ws + OWK1;
        dst = pk + PY1 + ((size_t)(ct * 4 + h) * 64 + l) * 8;
        #pragma unroll
        for (int idx = 0; idx < 8; ++idx)
            v[idx] = bf1(w[(ct * 16 + (l & 15)) * 128 + h * 32 + (l >> 4) * 8 + idx]);
    } else {                              // Y2 (16 ct x 4 h)
        const int b2 = bid - 128, ct = b2 >> 2, h = b2 & 3;
        w = ws + OWK2;
        dst = pk + PY2 + ((size_t)(ct * 4 + h) * 64 + l) * 8;
        #pragma unroll
        for (int idx = 0; idx < 8; ++idx)
            v[idx] = bf1(w[(ct * 16 + (l & 15)) * 128 + h * 32 + (l >> 4) * 8 + idx]);
    }
    uint4 u;
    u.x = (unsigned)(unsigned short)v[0] | ((unsigned)(unsigned short)v[1] << 16);
    u.y = (unsigned)(unsigned short)v[2] | ((unsigned)(unsigned short)v[3] << 16);
    u.z = (unsigned)(unsigned short)v[4] | ((unsigned)(unsigned short)v[5] << 16);
    u.w = (unsigned)(unsigned short)v[6] | ((unsigned)(unsigned short)v[7] << 16);
    *(uint4*)dst = u;
}

// ---------------------------------------------------------------------------
// Fused stage body (R8 structure) + Zc register prefetch so the PV (Zc)
// stream is in flight CONCURRENTLY with the score (HFc/zst) stream.
// ---------------------------------------------------------------------------
template <int STAGE>
__device__ __forceinline__ void stage_body(
    const float* __restrict__ HFs,
    const float* __restrict__ HFc,
    const float* __restrict__ Zc,
    const float* __restrict__ ws,
    const float* __restrict__ zst,
    float* __restrict__ out)
{
    constexpr int CQ  = (STAGE == 1) ? 128 : 256;
    constexpr int CK  = CQ;
    constexpr int NP  = CK / 128;
    constexpr int NKT = CQ / 32;
    constexpr int UNION_B = CK * 16 * 8;

    const float* qwt = ws + ((STAGE == 1) ? OWQ1 : OWQ2);
    const float* qb_ = ws + ((STAGE == 1) ? OBQ1 : OBQ2);
    const float* kwt = ws + ((STAGE == 1) ? OWK1 : OWK2);
    const float* kb_ = ws + ((STAGE == 1) ? OBK1 : OBK2);
    const short* pk  = (const short*)(ws + OPACK);
    const short* aQ  = pk + ((STAGE == 1) ? PQ1 : PQ2);
    const short* aY  = pk + ((STAGE == 1) ? PY1 : PY2);

    __shared__ __align__(16) char smem[UNION_B + 768 + 2304 + 2048 + 512];
    short* sXF = (short*)smem;
    short* sQF = (short*)(smem + CQ * 32);
    uint2* sYQ = (uint2*)smem;
    float* sRed = (float*)smem;
    float* sYX = (float*)(smem + UNION_B);
    float* sHW = sYX + 192;
    float* sSc = sHW + 576;
    float* sAW = sSc + 512;

    const int t   = threadIdx.x;
    const int l   = t & 63;
    const int wv  = t >> 6;
    const int bid = blockIdx.x;
    const int b   = bid >> 10;
    const int rem = bid & 1023;
    const int ks  = rem >> 7;
    const int hp  = rem & 127;
    const int r0  = ks * 2048 + hp * 16;

    const float ik = (float)hp * INV127;
    const float iq = (float)(r0 >> 7) * INV127;
    const int   w0 = r0 & 127;

    // ---- stage Xq into LDS fragment layout ----
    {
        const int qg = t & 3, c = t >> 2;
        #pragma unroll
        for (int r = 0; r < CQ / 64; ++r) {
            const int cc = c + r * 64;
            const float* src = (STAGE == 1 || cc < 128)
                ? HFs + ((size_t)(b * 128 + cc)) * HWc + r0 + qg * 4
                : zst + ((size_t)(b * 128 + cc - 128)) * HWc + r0 + qg * 4;
            const float4 x = *(const float4*)src;
            const int kt = cc >> 5, g = (cc & 31) >> 3, idx = cc & 7;
            short* dstb = &sXF[kt * 512 + idx + 16 * g * 8];
            dstb[(qg * 4 + 0) * 8] = bf1(x.x);
            dstb[(qg * 4 + 1) * 8] = bf1(x.y);
            dstb[(qg * 4 + 2) * 8] = bf1(x.z);
            dstb[(qg * 4 + 3) * 8] = bf1(x.w);
        }
    }
    __syncthreads();

    // ---- Phase Q (MFMA) ----
    {
        const float jqv = (float)(w0 + (l & 15)) * INV127;
        f32x4 acc0, acc1;
        #pragma unroll
        for (int r = 0; r < 4; ++r) {
            const int e0 = (wv * 2 + 0) * 16 + (l >> 4) * 4 + r;
            const int e1 = (wv * 2 + 1) * 16 + (l >> 4) * 4 + r;
            acc0[r] = qb_[e0] + iq * qwt[(size_t)CQ * 128 + e0]
                             + jqv * qwt[(size_t)(CQ + 1) * 128 + e0];
            acc1[r] = qb_[e1] + iq * qwt[(size_t)CQ * 128 + e1]
                             + jqv * qwt[(size_t)(CQ + 1) * 128 + e1];
        }
        #pragma unroll
        for (int kt = 0; kt < NKT; ++kt) {
            const short8 bfr = *(const short8*)&sXF[kt * 512 + l * 8];
            const short8 a0 = *(const short8*)&aQ[(((wv * 2 + 0) * NKT + kt) * 64 + l) * 8];
            const short8 a1 = *(const short8*)&aQ[(((wv * 2 + 1) * NKT + kt) * 64 + l) * 8];
            acc0 = __builtin_amdgcn_mfma_f32_16x16x32_bf16(a0, bfr, acc0, 0, 0, 0);
            acc1 = __builtin_amdgcn_mfma_f32_16x16x32_bf16(a1, bfr, acc1, 0, 0, 0);
        }
        __syncthreads();
        #pragma unroll
        for (int m = 0; m < 2; ++m) {
            const f32x4 a = m ? acc1 : acc0;
            const int e0 = (wv * 2 + m) * 16 + (l >> 4) * 4;
            const int kt = e0 >> 5, g = (e0 & 31) >> 3, idx0 = e0 & 7;
            uint2 u; u.x = bfpack(a[0], a[1]); u.y = bfpack(a[2], a[3]);
            *(uint2*)&sQF[kt * 512 + ((l & 15) + 16 * g) * 8 + idx0] = u;
        }
    }
    __syncthreads();

    // ---- coordinate / bias projections per head ----
    if (t < 192) {
        const int qq = t & 15, h = (t >> 4) & 3, which = t >> 6;
        const float* wrow = (which == 0) ? kwt + (size_t)CK * 128
                          : (which == 1) ? kwt + (size_t)(CK + 1) * 128
                                         : kb_;
        float acc = 0.f;
        #pragma unroll
        for (int e32 = 0; e32 < 32; ++e32) {
            const int e2 = h * 32 + e32;
            const int g = (e2 & 31) >> 3, idx = e2 & 7;
            acc += wrow[e2] * bf2f(sQF[h * 512 + (qq + 16 * g) * 8 + idx]);
        }
        sYX[(which * 4 + h) * 16 + qq] = acc;
    }

    const short8 bq0 = *(const short8*)&sQF[0 * 512 + l * 8];
    const short8 bq1 = *(const short8*)&sQF[1 * 512 + l * 8];
    const short8 bq2 = *(const short8*)&sQF[2 * 512 + l * 8];
    const short8 bq3 = *(const short8*)&sQF[3 * 512 + l * 8];
    __syncthreads();

    // ---- ALL Phase-Y passes (MFMA -> sYQ[c][16]) ----
    {
        const f32x4 zf = {0.f, 0.f, 0.f, 0.f};
        #pragma unroll
        for (int p = 0; p < NP; ++p) {
            #pragma unroll
            for (int m = 0; m < 2; ++m) {
                const int ct = p * 8 + wv * 2 + m;
                const short8 y0 = *(const short8*)&aY[(((ct * 4) + 0) * 64 + l) * 8];
                const short8 y1 = *(const short8*)&aY[(((ct * 4) + 1) * 64 + l) * 8];
                const short8 y2 = *(const short8*)&aY[(((ct * 4) + 2) * 64 + l) * 8];
                const short8 y3 = *(const short8*)&aY[(((ct * 4) + 3) * 64 + l) * 8];
                f32x4 d0 = __builtin_amdgcn_mfma_f32_16x16x32_bf16(y0, bq0, zf, 0, 0, 0);
                f32x4 d1 = __builtin_amdgcn_mfma_f32_16x16x32_bf16(y1, bq1, zf, 0, 0, 0);
                f32x4 d2 = __builtin_amdgcn_mfma_f32_16x16x32_bf16(y2, bq2, zf, 0, 0, 0);
                f32x4 d3 = __builtin_amdgcn_mfma_f32_16x16x32_bf16(y3, bq3, zf, 0, 0, 0);
                #pragma unroll
                for (int r = 0; r < 4; ++r) {
                    const int cg = ct * 16 + (l >> 4) * 4 + r;
                    uint2 u;
                    u.x = bfpack(d0[r], d1[r]);
                    u.y = bfpack(d2[r], d3[r]);
                    sYQ[cg * 16 + (l & 15)] = u;
                }
            }
        }
    }
    __syncthreads();

    // ---- PV prefetch: issue ALL Zc loads now; they fly during the score
    //      stream. Values are held in VGPRs until the PV epilogue. ----
    const int pidx = t & 15, pcg = t >> 4;
    const int pc8  = pcg * 8;
    const float* zb = Zc + (((size_t)(b * Kc + ks)) * 128 + pc8) * HWc
                    + hp * 128 + pidx * 8;
    float4 zp[16];
    #pragma unroll
    for (int i = 0; i < 8; ++i) {
        zp[2 * i]     = *(const float4*)(zb + (size_t)i * HWc);
        zp[2 * i + 1] = *(const float4*)(zb + (size_t)i * HWc + 4);
    }

    // ---- score: unbroken load stream ----
    const int pg = t & 31;
    const int cs = t >> 5;
    const int q  = pg >> 1;
    float acc[4][4];
    #pragma unroll
    for (int h = 0; h < 4; ++h)
        #pragma unroll
        for (int j = 0; j < 4; ++j) acc[h][j] = 0.f;

    #pragma unroll
    for (int half = 0; half < NP; ++half) {
        const int cbase = half * 128 + cs * 16;
        const float* xp = (STAGE == 1 || half == 0)
            ? HFc + (((size_t)(b * Kc + ks)) * 128 + cbase) * HWc + hp * 128 + pg * 4
            : zst + ((size_t)(b * 128 + cs * 16)) * HWc + hp * 128 + pg * 4;
        const uint2* yqp = &sYQ[cbase * 16 + q];
        #pragma unroll 8
        for (int cc = 0; cc < 16; ++cc) {
            const float4 x = *(const float4*)(xp + (size_t)cc * HWc);
            fma16(acc, yqp[cc * 16], x);
        }
    }

    // ---- reduce over cs ----
    #pragma unroll
    for (int h = 0; h < 4; ++h)
        #pragma unroll
        for (int j = 0; j < 4; ++j)
            acc[h][j] += __shfl_xor(acc[h][j], 32, 64);
    __syncthreads();
    if (l < 32) {
        #pragma unroll
        for (int h = 0; h < 4; ++h)
            #pragma unroll
            for (int j = 0; j < 4; ++j)
                sRed[wv * 512 + pg * 16 + h * 4 + j] = acc[h][j];
    }
    __syncthreads();

    if (t < 128) {
        const int pos = t, pgg = pos >> 2, j = pos & 3, qq = pos >> 3;
        const float jk = (float)pos * INV127;
        #pragma unroll
        for (int h = 0; h < 4; ++h) {
            const float v = sRed[0 * 512 + pgg * 16 + h * 4 + j]
                          + sRed[1 * 512 + pgg * 16 + h * 4 + j]
                          + sRed[2 * 512 + pgg * 16 + h * 4 + j]
                          + sRed[3 * 512 + pgg * 16 + h * 4 + j];
            const float s = v + ik * sYX[(0 * 4 + h) * 16 + qq]
                              + jk * sYX[(1 * 4 + h) * 16 + qq]
                              +      sYX[(2 * 4 + h) * 16 + qq];
            sSc[h * 128 + pos] = s * SCALE;
        }
    }
    __syncthreads();

    // ---- softmax per (q, head) on 64 lanes, then combine on 16 ----
    if (t < 64) {
        const int qq = t & 15, h = t >> 4;
        float sc[8], m = -INFINITY;
        #pragma unroll
        for (int j = 0; j < 8; ++j) {
            sc[j] = sSc[h * 128 + qq * 8 + j];
            m = fmaxf(m, sc[j]);
        }
        float sum = 0.f;
        #pragma unroll
        for (int j = 0; j < 8; ++j) { sc[j] = __expf(sc[j] - m); sum += sc[j]; }
        const float inv = 0.25f / sum;
        #pragma unroll
        for (int j = 0; j < 8; ++j) sHW[(h * 16 + qq) * 9 + j] = sc[j] * inv;
    }
    __syncthreads();
    if (t < 16) {
        float at[8];
        float n2 = 0.f;
        #pragma unroll
        for (int j = 0; j < 8; ++j) {
            at[j] = sHW[(0 * 16 + t) * 9 + j] + sHW[(1 * 16 + t) * 9 + j]
                  + sHW[(2 * 16 + t) * 9 + j] + sHW[(3 * 16 + t) * 9 + j];
            n2 += at[j] * at[j];
        }
        const float nrm = fmaxf(sqrtf(n2), 1e-12f);
        #pragma unroll
        for (int j = 0; j < 8; ++j) sAW[t * 8 + j] = at[j] / nrm;
    }
    __syncthreads();

    // ---- PV epilogue: uses prefetched Zc registers ----
    {
        const float4 a0 = *(const float4*)&sAW[pidx * 8];
        const float4 a1 = *(const float4*)&sAW[pidx * 8 + 4];
        float* ob = out + ((size_t)(b * 128 + pc8)) * HWc + r0 + pidx;
        #pragma unroll
        for (int i = 0; i < 8; ++i) {
            ob[(size_t)i * HWc] =
                a0.x * zp[2 * i].x + a0.y * zp[2 * i].y +
                a0.z * zp[2 * i].z + a0.w * zp[2 * i].w +
                a1.x * zp[2 * i + 1].x + a1.y * zp[2 * i + 1].y +
                a1.z * zp[2 * i + 1].z + a1.w * zp[2 * i + 1].w;
        }
    }
}

__global__ __launch_bounds__(256) void stage1_kernel(
    const float* __restrict__ HFs, const float* __restrict__ HFc,
    const float* __restrict__ Zc,  const float* __restrict__ ws,
    const float* __restrict__ zst, float* __restrict__ out)
{
    stage_body<1>(HFs, HFc, Zc, ws, zst, out);
}

__global__ __launch_bounds__(256) void stage2_kernel(
    const float* __restrict__ HFs, const float* __restrict__ HFc,
    const float* __restrict__ Zc,  const float* __restrict__ ws,
    const float* __restrict__ zst, float* __restrict__ out)
{
    stage_body<2>(HFs, HFc, Zc, ws, zst, out);
}

// ---------------------------------------------------------------------------
extern "C" void kernel_launch(void* const* d_in, const int* in_sizes, int n_in,
                              void* d_out, int out_size, void* d_ws, size_t ws_size,
                              hipStream_t stream)
{
    const float* HFs = (const float*)d_in[0];
    const float* HFc = (const float*)d_in[1];
    const float* Zc  = (const float*)d_in[2];
    float* ws    = (float*)d_ws;
    float* zstar = (float*)d_out;
    float* zhat  = zstar + (size_t)Bc * 128 * HWc;

    prep_kernel<<<1040, 128, 0, stream>>>(
        (const float*)d_in[3],  (const float*)d_in[4],
        (const float*)d_in[5],  (const float*)d_in[6],
        (const float*)d_in[7],  (const float*)d_in[8],
        (const float*)d_in[9],  (const float*)d_in[10],
        (const float*)d_in[11], (const float*)d_in[12],
        (const float*)d_in[13], (const float*)d_in[14],
        (const float*)d_in[15], (const float*)d_in[16],
        (const float*)d_in[17], (const float*)d_in[18],
        ws);

    pack_kernel<<<192, 64, 0, stream>>>(ws);

    stage1_kernel<<<2048, 256, 0, stream>>>(HFs, HFc, Zc, ws, zstar, zstar);
    stage2_kernel<<<2048, 256, 0, stream>>>(HFs, HFc, Zc, ws, zstar, zhat);
}

// Round 13
// 150.411 us; speedup vs baseline: 1.2317x; 1.2317x over previous
//
#include <hip/hip_runtime.h>
#include <math.h>

constexpr int Bc = 2, Kc = 8, HWc = 16384;
constexpr float SCALE  = 0.17677669529663687f;  // 1/sqrt(32)
constexpr float INV127 = 1.0f / 127.0f;

using short8 = __attribute__((ext_vector_type(8))) short;
using f32x4  = __attribute__((ext_vector_type(4))) float;

// ws layout (floats). owt = combined (attn_w @ layer_w), d-major: owt[d][e].
constexpr int OWQ1 = 0;
constexpr int OBQ1 = OWQ1 + 130 * 128;
constexpr int OWK1 = OBQ1 + 128;
constexpr int OBK1 = OWK1 + 130 * 128;
constexpr int OWQ2 = OBK1 + 128;
constexpr int OBQ2 = OWQ2 + 258 * 128;
constexpr int OWK2 = OBQ2 + 128;
constexpr int OBK2 = OWK2 + 258 * 128;
constexpr int OPACK = OBK2 + 128;       // short region: packed MFMA A-fragments
constexpr int PQ1 = 0;
constexpr int PQ2 = PQ1 + 32 * 512;
constexpr int PY1 = PQ2 + 64 * 512;
constexpr int PY2 = PY1 + 32 * 512;

__device__ __forceinline__ unsigned bfpack(float a, float b) {
    unsigned ua = __float_as_uint(a); ua = (ua + 0x7FFFu + ((ua >> 16) & 1u)) >> 16;
    unsigned ub = __float_as_uint(b); ub = (ub + 0x7FFFu + ((ub >> 16) & 1u)) >> 16;
    return ua | (ub << 16);
}
__device__ __forceinline__ short bf1(float a) {
    unsigned ua = __float_as_uint(a); ua = (ua + 0x7FFFu + ((ua >> 16) & 1u)) >> 16;
    return (short)ua;
}
__device__ __forceinline__ float bflo(unsigned u) { return __uint_as_float(u << 16); }
__device__ __forceinline__ float bfhi(unsigned u) { return __uint_as_float(u & 0xFFFF0000u); }
__device__ __forceinline__ float bf2f(short s) {
    return __uint_as_float(((unsigned)(unsigned short)s) << 16);
}

__device__ __forceinline__ void fma16(float (&a)[4][4], uint2 u, float4 x) {
    const float y0 = bflo(u.x), y1 = bfhi(u.x), y2 = bflo(u.y), y3 = bfhi(u.y);
    a[0][0] += y0 * x.x; a[0][1] += y0 * x.y; a[0][2] += y0 * x.z; a[0][3] += y0 * x.w;
    a[1][0] += y1 * x.x; a[1][1] += y1 * x.y; a[1][2] += y1 * x.z; a[1][3] += y1 * x.w;
    a[2][0] += y2 * x.x; a[2][1] += y2 * x.y; a[2][2] += y2 * x.z; a[2][3] += y2 * x.w;
    a[3][0] += y3 * x.x; a[3][1] += y3 * x.y; a[3][2] += y3 * x.z; a[3][3] += y3 * x.w;
}

// ---------------------------------------------------------------------------
__global__ __launch_bounds__(128) void prep_kernel(
    const float* __restrict__ q1w, const float* __restrict__ q1b,
    const float* __restrict__ k1w, const float* __restrict__ k1b,
    const float* __restrict__ a1qw, const float* __restrict__ a1qb,
    const float* __restrict__ a1kw, const float* __restrict__ a1kb,
    const float* __restrict__ q2w, const float* __restrict__ q2b,
    const float* __restrict__ k2w, const float* __restrict__ k2b,
    const float* __restrict__ a2qw, const float* __restrict__ a2qb,
    const float* __restrict__ a2kw, const float* __restrict__ a2kb,
    float* __restrict__ ws)
{
    const int job = blockIdx.x / 260;
    const int d   = blockIdx.x % 260;
    const float *aw, *ab, *w, *wb;
    float *owt, *ob;
    int D;
    if (job == 0)      { aw=a1qw; ab=a1qb; w=q1w; wb=q1b; owt=ws+OWQ1; ob=ws+OBQ1; D=130; }
    else if (job == 1) { aw=a1kw; ab=a1kb; w=k1w; wb=k1b; owt=ws+OWK1; ob=ws+OBK1; D=130; }
    else if (job == 2) { aw=a2qw; ab=a2qb; w=q2w; wb=q2b; owt=ws+OWQ2; ob=ws+OBQ2; D=258; }
    else               { aw=a2kw; ab=a2kb; w=k2w; wb=k2b; owt=ws+OWK2; ob=ws+OBK2; D=258; }
    const int e = threadIdx.x;
    if (d < D) {
        float acc = 0.f;
        for (int f = 0; f < 128; ++f) acc += aw[e * 128 + f] * w[f * D + d];
        owt[d * 128 + e] = acc;
    } else if (d == D) {
        float acc = ab[e];
        for (int f = 0; f < 128; ++f) acc += aw[e * 128 + f] * wb[f];
        ob[e] = acc;
    }
}

// ---------------------------------------------------------------------------
// pack: MFMA A-fragments (bf16): element(lane,idx) = A[i][k],
// i = lane&15, k = 8*(lane>>4)+idx.
// ---------------------------------------------------------------------------
__global__ __launch_bounds__(64) void pack_kernel(float* __restrict__ ws)
{
    short* pk = (short*)(ws + OPACK);
    const int l = threadIdx.x, bid = blockIdx.x;
    const float* w;
    short* dst;
    short v[8];
    if (bid < 32) {                       // Q1 (NKT=4)
        const int et = bid >> 2, kt = bid & 3;
        w = ws + OWQ1;
        dst = pk + PQ1 + ((size_t)(et * 4 + kt) * 64 + l) * 8;
        #pragma unroll
        for (int idx = 0; idx < 8; ++idx)
            v[idx] = bf1(w[(kt * 32 + (l >> 4) * 8 + idx) * 128 + et * 16 + (l & 15)]);
    } else if (bid < 96) {                // Q2 (NKT=8)
        const int b2 = bid - 32, et = b2 >> 3, kt = b2 & 7;
        w = ws + OWQ2;
        dst = pk + PQ2 + ((size_t)(et * 8 + kt) * 64 + l) * 8;
        #pragma unroll
        for (int idx = 0; idx < 8; ++idx)
            v[idx] = bf1(w[(kt * 32 + (l >> 4) * 8 + idx) * 128 + et * 16 + (l & 15)]);
    } else if (bid < 128) {               // Y1 (8 ct x 4 h)
        const int b2 = bid - 96, ct = b2 >> 2, h = b2 & 3;
        w = ws + OWK1;
        dst = pk + PY1 + ((size_t)(ct * 4 + h) * 64 + l) * 8;
        #pragma unroll
        for (int idx = 0; idx < 8; ++idx)
            v[idx] = bf1(w[(ct * 16 + (l & 15)) * 128 + h * 32 + (l >> 4) * 8 + idx]);
    } else {                              // Y2 (16 ct x 4 h)
        const int b2 = bid - 128, ct = b2 >> 2, h = b2 & 3;
        w = ws + OWK2;
        dst = pk + PY2 + ((size_t)(ct * 4 + h) * 64 + l) * 8;
        #pragma unroll
        for (int idx = 0; idx < 8; ++idx)
            v[idx] = bf1(w[(ct * 16 + (l & 15)) * 128 + h * 32 + (l >> 4) * 8 + idx]);
    }
    uint4 u;
    u.x = (unsigned)(unsigned short)v[0] | ((unsigned)(unsigned short)v[1] << 16);
    u.y = (unsigned)(unsigned short)v[2] | ((unsigned)(unsigned short)v[3] << 16);
    u.z = (unsigned)(unsigned short)v[4] | ((unsigned)(unsigned short)v[5] << 16);
    u.w = (unsigned)(unsigned short)v[6] | ((unsigned)(unsigned short)v[7] << 16);
    *(uint4*)dst = u;
}

// ---------------------------------------------------------------------------
// Fused stage body (R8 structure — best measured). PV loads stay in the
// epilogue: holding them in VGPRs across the score stream cost occupancy
// (R12: 38%->30%, +10us). Streaming-bound; see journal for the roofline calc.
// ---------------------------------------------------------------------------
template <int STAGE>
__device__ __forceinline__ void stage_body(
    const float* __restrict__ HFs,
    const float* __restrict__ HFc,
    const float* __restrict__ Zc,
    const float* __restrict__ ws,
    const float* __restrict__ zst,
    float* __restrict__ out)
{
    constexpr int CQ  = (STAGE == 1) ? 128 : 256;
    constexpr int CK  = CQ;
    constexpr int NP  = CK / 128;
    constexpr int NKT = CQ / 32;
    constexpr int UNION_B = CK * 16 * 8;

    const float* qwt = ws + ((STAGE == 1) ? OWQ1 : OWQ2);
    const float* qb_ = ws + ((STAGE == 1) ? OBQ1 : OBQ2);
    const float* kwt = ws + ((STAGE == 1) ? OWK1 : OWK2);
    const float* kb_ = ws + ((STAGE == 1) ? OBK1 : OBK2);
    const short* pk  = (const short*)(ws + OPACK);
    const short* aQ  = pk + ((STAGE == 1) ? PQ1 : PQ2);
    const short* aY  = pk + ((STAGE == 1) ? PY1 : PY2);

    __shared__ __align__(16) char smem[UNION_B + 768 + 2304 + 2048 + 512];
    short* sXF = (short*)smem;
    short* sQF = (short*)(smem + CQ * 32);
    uint2* sYQ = (uint2*)smem;
    float* sRed = (float*)smem;
    float* sYX = (float*)(smem + UNION_B);
    float* sHW = sYX + 192;
    float* sSc = sHW + 576;
    float* sAW = sSc + 512;

    const int t   = threadIdx.x;
    const int l   = t & 63;
    const int wv  = t >> 6;
    const int bid = blockIdx.x;
    const int b   = bid >> 10;
    const int rem = bid & 1023;
    const int ks  = rem >> 7;
    const int hp  = rem & 127;
    const int r0  = ks * 2048 + hp * 16;

    const float ik = (float)hp * INV127;
    const float iq = (float)(r0 >> 7) * INV127;
    const int   w0 = r0 & 127;

    // ---- stage Xq into LDS fragment layout ----
    {
        const int qg = t & 3, c = t >> 2;
        #pragma unroll
        for (int r = 0; r < CQ / 64; ++r) {
            const int cc = c + r * 64;
            const float* src = (STAGE == 1 || cc < 128)
                ? HFs + ((size_t)(b * 128 + cc)) * HWc + r0 + qg * 4
                : zst + ((size_t)(b * 128 + cc - 128)) * HWc + r0 + qg * 4;
            const float4 x = *(const float4*)src;
            const int kt = cc >> 5, g = (cc & 31) >> 3, idx = cc & 7;
            short* dstb = &sXF[kt * 512 + idx + 16 * g * 8];
            dstb[(qg * 4 + 0) * 8] = bf1(x.x);
            dstb[(qg * 4 + 1) * 8] = bf1(x.y);
            dstb[(qg * 4 + 2) * 8] = bf1(x.z);
            dstb[(qg * 4 + 3) * 8] = bf1(x.w);
        }
    }
    __syncthreads();

    // ---- Phase Q (MFMA) ----
    {
        const float jqv = (float)(w0 + (l & 15)) * INV127;
        f32x4 acc0, acc1;
        #pragma unroll
        for (int r = 0; r < 4; ++r) {
            const int e0 = (wv * 2 + 0) * 16 + (l >> 4) * 4 + r;
            const int e1 = (wv * 2 + 1) * 16 + (l >> 4) * 4 + r;
            acc0[r] = qb_[e0] + iq * qwt[(size_t)CQ * 128 + e0]
                             + jqv * qwt[(size_t)(CQ + 1) * 128 + e0];
            acc1[r] = qb_[e1] + iq * qwt[(size_t)CQ * 128 + e1]
                             + jqv * qwt[(size_t)(CQ + 1) * 128 + e1];
        }
        #pragma unroll
        for (int kt = 0; kt < NKT; ++kt) {
            const short8 bfr = *(const short8*)&sXF[kt * 512 + l * 8];
            const short8 a0 = *(const short8*)&aQ[(((wv * 2 + 0) * NKT + kt) * 64 + l) * 8];
            const short8 a1 = *(const short8*)&aQ[(((wv * 2 + 1) * NKT + kt) * 64 + l) * 8];
            acc0 = __builtin_amdgcn_mfma_f32_16x16x32_bf16(a0, bfr, acc0, 0, 0, 0);
            acc1 = __builtin_amdgcn_mfma_f32_16x16x32_bf16(a1, bfr, acc1, 0, 0, 0);
        }
        __syncthreads();
        #pragma unroll
        for (int m = 0; m < 2; ++m) {
            const f32x4 a = m ? acc1 : acc0;
            const int e0 = (wv * 2 + m) * 16 + (l >> 4) * 4;
            const int kt = e0 >> 5, g = (e0 & 31) >> 3, idx0 = e0 & 7;
            uint2 u; u.x = bfpack(a[0], a[1]); u.y = bfpack(a[2], a[3]);
            *(uint2*)&sQF[kt * 512 + ((l & 15) + 16 * g) * 8 + idx0] = u;
        }
    }
    __syncthreads();

    // ---- coordinate / bias projections per head ----
    if (t < 192) {
        const int qq = t & 15, h = (t >> 4) & 3, which = t >> 6;
        const float* wrow = (which == 0) ? kwt + (size_t)CK * 128
                          : (which == 1) ? kwt + (size_t)(CK + 1) * 128
                                         : kb_;
        float acc = 0.f;
        #pragma unroll
        for (int e32 = 0; e32 < 32; ++e32) {
            const int e2 = h * 32 + e32;
            const int g = (e2 & 31) >> 3, idx = e2 & 7;
            acc += wrow[e2] * bf2f(sQF[h * 512 + (qq + 16 * g) * 8 + idx]);
        }
        sYX[(which * 4 + h) * 16 + qq] = acc;
    }

    const short8 bq0 = *(const short8*)&sQF[0 * 512 + l * 8];
    const short8 bq1 = *(const short8*)&sQF[1 * 512 + l * 8];
    const short8 bq2 = *(const short8*)&sQF[2 * 512 + l * 8];
    const short8 bq3 = *(const short8*)&sQF[3 * 512 + l * 8];
    __syncthreads();

    // ---- ALL Phase-Y passes (MFMA -> sYQ[c][16]) ----
    {
        const f32x4 zf = {0.f, 0.f, 0.f, 0.f};
        #pragma unroll
        for (int p = 0; p < NP; ++p) {
            #pragma unroll
            for (int m = 0; m < 2; ++m) {
                const int ct = p * 8 + wv * 2 + m;
                const short8 y0 = *(const short8*)&aY[(((ct * 4) + 0) * 64 + l) * 8];
                const short8 y1 = *(const short8*)&aY[(((ct * 4) + 1) * 64 + l) * 8];
                const short8 y2 = *(const short8*)&aY[(((ct * 4) + 2) * 64 + l) * 8];
                const short8 y3 = *(const short8*)&aY[(((ct * 4) + 3) * 64 + l) * 8];
                f32x4 d0 = __builtin_amdgcn_mfma_f32_16x16x32_bf16(y0, bq0, zf, 0, 0, 0);
                f32x4 d1 = __builtin_amdgcn_mfma_f32_16x16x32_bf16(y1, bq1, zf, 0, 0, 0);
                f32x4 d2 = __builtin_amdgcn_mfma_f32_16x16x32_bf16(y2, bq2, zf, 0, 0, 0);
                f32x4 d3 = __builtin_amdgcn_mfma_f32_16x16x32_bf16(y3, bq3, zf, 0, 0, 0);
                #pragma unroll
                for (int r = 0; r < 4; ++r) {
                    const int cg = ct * 16 + (l >> 4) * 4 + r;
                    uint2 u;
                    u.x = bfpack(d0[r], d1[r]);
                    u.y = bfpack(d2[r], d3[r]);
                    sYQ[cg * 16 + (l & 15)] = u;
                }
            }
        }
    }
    __syncthreads();

    // ---- score: ONE unbroken load stream, no barriers ----
    const int pg = t & 31;
    const int cs = t >> 5;
    const int q  = pg >> 1;
    float acc[4][4];
    #pragma unroll
    for (int h = 0; h < 4; ++h)
        #pragma unroll
        for (int j = 0; j < 4; ++j) acc[h][j] = 0.f;

    #pragma unroll
    for (int half = 0; half < NP; ++half) {
        const int cbase = half * 128 + cs * 16;
        const float* xp = (STAGE == 1 || half == 0)
            ? HFc + (((size_t)(b * Kc + ks)) * 128 + cbase) * HWc + hp * 128 + pg * 4
            : zst + ((size_t)(b * 128 + cs * 16)) * HWc + hp * 128 + pg * 4;
        const uint2* yqp = &sYQ[cbase * 16 + q];
        #pragma unroll 8
        for (int cc = 0; cc < 16; ++cc) {
            const float4 x = *(const float4*)(xp + (size_t)cc * HWc);
            fma16(acc, yqp[cc * 16], x);
        }
    }

    // ---- reduce over cs ----
    #pragma unroll
    for (int h = 0; h < 4; ++h)
        #pragma unroll
        for (int j = 0; j < 4; ++j)
            acc[h][j] += __shfl_xor(acc[h][j], 32, 64);
    __syncthreads();
    if (l < 32) {
        #pragma unroll
        for (int h = 0; h < 4; ++h)
            #pragma unroll
            for (int j = 0; j < 4; ++j)
                sRed[wv * 512 + pg * 16 + h * 4 + j] = acc[h][j];
    }
    __syncthreads();

    if (t < 128) {
        const int pos = t, pgg = pos >> 2, j = pos & 3, qq = pos >> 3;
        const float jk = (float)pos * INV127;
        #pragma unroll
        for (int h = 0; h < 4; ++h) {
            const float v = sRed[0 * 512 + pgg * 16 + h * 4 + j]
                          + sRed[1 * 512 + pgg * 16 + h * 4 + j]
                          + sRed[2 * 512 + pgg * 16 + h * 4 + j]
                          + sRed[3 * 512 + pgg * 16 + h * 4 + j];
            const float s = v + ik * sYX[(0 * 4 + h) * 16 + qq]
                              + jk * sYX[(1 * 4 + h) * 16 + qq]
                              +      sYX[(2 * 4 + h) * 16 + qq];
            sSc[h * 128 + pos] = s * SCALE;
        }
    }
    __syncthreads();

    // ---- softmax per (q, head) on 64 lanes, then combine on 16 ----
    if (t < 64) {
        const int qq = t & 15, h = t >> 4;
        float sc[8], m = -INFINITY;
        #pragma unroll
        for (int j = 0; j < 8; ++j) {
            sc[j] = sSc[h * 128 + qq * 8 + j];
            m = fmaxf(m, sc[j]);
        }
        float sum = 0.f;
        #pragma unroll
        for (int j = 0; j < 8; ++j) { sc[j] = __expf(sc[j] - m); sum += sc[j]; }
        const float inv = 0.25f / sum;
        #pragma unroll
        for (int j = 0; j < 8; ++j) sHW[(h * 16 + qq) * 9 + j] = sc[j] * inv;
    }
    __syncthreads();
    if (t < 16) {
        float at[8];
        float n2 = 0.f;
        #pragma unroll
        for (int j = 0; j < 8; ++j) {
            at[j] = sHW[(0 * 16 + t) * 9 + j] + sHW[(1 * 16 + t) * 9 + j]
                  + sHW[(2 * 16 + t) * 9 + j] + sHW[(3 * 16 + t) * 9 + j];
            n2 += at[j] * at[j];
        }
        const float nrm = fmaxf(sqrtf(n2), 1e-12f);
        #pragma unroll
        for (int j = 0; j < 8; ++j) sAW[t * 8 + j] = at[j] / nrm;
    }
    __syncthreads();

    // ---- PV: weighted sum of raw values (direct coalesced global reads) ----
    {
        const int idx = t & 15, cg = t >> 4;
        const int c8  = cg * 8;
        const float4 a0 = *(const float4*)&sAW[idx * 8];
        const float4 a1 = *(const float4*)&sAW[idx * 8 + 4];
        const float* zb = Zc + (((size_t)(b * Kc + ks)) * 128 + c8) * HWc + hp * 128 + idx * 8;
        float* ob = out + ((size_t)(b * 128 + c8)) * HWc + r0 + idx;
        #pragma unroll
        for (int i = 0; i < 8; ++i) {
            const float4 z0 = *(const float4*)(zb + (size_t)i * HWc);
            const float4 z1 = *(const float4*)(zb + (size_t)i * HWc + 4);
            ob[(size_t)i * HWc] =
                a0.x * z0.x + a0.y * z0.y + a0.z * z0.z + a0.w * z0.w +
                a1.x * z1.x + a1.y * z1.y + a1.z * z1.z + a1.w * z1.w;
        }
    }
}

__global__ __launch_bounds__(256) void stage1_kernel(
    const float* __restrict__ HFs, const float* __restrict__ HFc,
    const float* __restrict__ Zc,  const float* __restrict__ ws,
    const float* __restrict__ zst, float* __restrict__ out)
{
    stage_body<1>(HFs, HFc, Zc, ws, zst, out);
}

__global__ __launch_bounds__(256) void stage2_kernel(
    const float* __restrict__ HFs, const float* __restrict__ HFc,
    const float* __restrict__ Zc,  const float* __restrict__ ws,
    const float* __restrict__ zst, float* __restrict__ out)
{
    stage_body<2>(HFs, HFc, Zc, ws, zst, out);
}

// ---------------------------------------------------------------------------
extern "C" void kernel_launch(void* const* d_in, const int* in_sizes, int n_in,
                              void* d_out, int out_size, void* d_ws, size_t ws_size,
                              hipStream_t stream)
{
    const float* HFs = (const float*)d_in[0];
    const float* HFc = (const float*)d_in[1];
    const float* Zc  = (const float*)d_in[2];
    float* ws    = (float*)d_ws;
    float* zstar = (float*)d_out;
    float* zhat  = zstar + (size_t)Bc * 128 * HWc;

    prep_kernel<<<1040, 128, 0, stream>>>(
        (const float*)d_in[3],  (const float*)d_in[4],
        (const float*)d_in[5],  (const float*)d_in[6],
        (const float*)d_in[7],  (const float*)d_in[8],
        (const float*)d_in[9],  (const float*)d_in[10],
        (const float*)d_in[11], (const float*)d_in[12],
        (const float*)d_in[13], (const float*)d_in[14],
        (const float*)d_in[15], (const float*)d_in[16],
        (const float*)d_in[17], (const float*)d_in[18],
        ws);

    pack_kernel<<<192, 64, 0, stream>>>(ws);

    stage1_kernel<<<2048, 256, 0, stream>>>(HFs, HFc, Zc, ws, zstar, zstar);
    stage2_kernel<<<2048, 256, 0, stream>>>(HFs, HFc, Zc, ws, zstar, zhat);
}